// Round 15
// baseline (97.484 us; speedup 1.0000x reference)
//
#include <hip/hip_runtime.h>

// Smoothness loss, 1x3x224x224 f32, scalar f32 out.
// r11 geometry (32x2 tiles, 784 blocks, 7 waves; wave wv owns rows
// wv, wv+7, wv+14; rolled row loop; interior/border variants; float4+float2
// LDS packing). r14 change: BATCHED LDS LOADS — per row, 3 phases of
// {load 7 neighbors into register arrays (14 ds_reads), then compute 7}
// -> 3 latency events/row instead of 21.

#define WSR 10
#define KK  21
#define HH  224
#define WW  224
#define HWSZ (HH*WW)
#define SIG_COLOR 50.0f
#define LPW 0.8f
#define C1T 10.0f
#define C2T 5.0f
#define ALPHA_W 5.0f
#define EPSV 1e-6f
#define LOG2E 1.44269504088896f
#define NSC (-SIG_COLOR * LOG2E)     // exp(-sc*cd) = exp2(NSC*cd)
#define SSP ((1.0f/98.0f) * LOG2E)   // exp(-d^2/98) = exp2(-SSP*d^2)

#define TX 32
#define TY 2
#define HALO_W (TX + 2*WSR)      // 52
#define HALO_H (TY + 2*WSR)      // 22
#define HSZ (HALO_W * HALO_H)    // 1144
#define NBX (WW / TX)            // 7
#define NBY (HH / TY)            // 112
#define NBLK (NBX * NBY)         // 784
#define NTHR 448
#define SCALEF (1.0f / ((float)HWSZ * 100.0f))
#define EPS_CORR (1323.0f * EPSV)    // 441 neighbors * 3 channels * eps

__device__ __forceinline__ float fexp2(float x) { return __builtin_amdgcn_exp2f(x); }
__device__ __forceinline__ float flog2(float x) { return __builtin_amdgcn_logf(x); }

template<bool B> struct BoolC { static constexpr bool value = B; };

// exp(-(k-10)^2/98) as compile-time literals
static constexpr float WXT[KK] = {
  0.3604486f, 0.4375650f, 0.5204496f, 0.6065307f, 0.6925675f,
  0.7748383f, 0.8493658f, 0.9122539f, 0.9600054f, 0.9898479f,
  1.0f,
  0.9898479f, 0.9600054f, 0.9122539f, 0.8493658f, 0.7748383f,
  0.6925675f, 0.6065307f, 0.5204496f, 0.4375650f, 0.3604486f };

__global__ __launch_bounds__(NTHR) void smooth_loss_fused(
    const float* __restrict__ orig, const float* __restrict__ smo,
    float* __restrict__ out)
{
    __shared__ float4 tAB[HSZ];   // (o0, o1, o2, s0)
    __shared__ float2 tC[HSZ];    // (s1, s2)
    __shared__ float racc0[NTHR], racc1[NTHR], racc2[NTHR], racc3[NTHR];

    const int tid = threadIdx.x;
    const int bid = blockIdx.x;
    const int bx  = bid % NBX;
    const int by  = bid / NBX;           // pixel-row-pair 0..111

    // ---- stage zero-padded halo tile (52 x 22) ----
    const int gx0 = bx * TX - WSR;
    const int gy0 = by * TY - WSR;
    for (int i = tid; i < HSZ; i += NTHR) {
        int r = i / HALO_W;
        int c = i - r * HALO_W;
        int gy = gy0 + r, gx = gx0 + c;
        bool v = ((unsigned)gy < (unsigned)HH) & ((unsigned)gx < (unsigned)WW);
        int gi = gy * WW + gx;
        float o0=0.f,o1=0.f,o2=0.f,s0=0.f,s1=0.f,s2=0.f;
        if (v) {
            o0 = orig[gi]; o1 = orig[gi+HWSZ]; o2 = orig[gi+2*HWSZ];
            s0 = smo[gi];  s1 = smo[gi+HWSZ]; s2 = smo[gi+2*HWSZ];
        }
        tAB[i] = make_float4(o0,o1,o2,s0);
        tC[i]  = make_float2(s1,s2);
    }
    __syncthreads();

    // ---- window scan: wave wv handles rows {wv, wv+7, wv+14} ----
    const int lane = tid & 63;
    const int wv   = tid >> 6;           // 0..6
    const int pr   = lane >> 5;          // pixel row in tile (0..1)
    const int pc   = lane & 31;          // pixel col in tile

    const int cpos = (WSR + pr) * HALO_W + (WSR + pc);
    const float4 cAB = tAB[cpos]; const float2 cC = tC[cpos];
    const float oc0=cAB.x, oc1=cAB.y, oc2=cAB.z, sc0=cAB.w, sc1=cC.x, sc2=cC.y;

    float er_o=0.f, er_u=0.f, sl=0.f, ss=0.f;   // er_u = sum(|d|+eps)

    // interior tile: whole 52x22 halo inside image -> masks provably true
    const bool interior = (bx >= 1) & (bx <= 5) & (by >= 5) & (by <= 106);

    auto scan = [&](auto mc) {
        constexpr bool MASKED = decltype(mc)::value;
        #pragma unroll 1                     // rolled: body = 1 row
        for (int r = 0; r < 3; ++r) {
            const int ky = wv + 7 * r;       // 0..20, each exactly once
            const float dyf = (float)(ky - WSR);
            const float wy = fexp2(-SSP * dyf * dyf);
            const int rbase = (pr + ky) * HALO_W + pc;
            const float4* __restrict__ rAB = &tAB[rbase];
            const float2* __restrict__ rC  = &tC[rbase];
            float srow = 0.f;
            #pragma unroll
            for (int ph = 0; ph < 3; ++ph) {
                // batch-load 7 neighbors into registers (static indices)
                float4 ab[7]; float2 cb[7];
                #pragma unroll
                for (int j = 0; j < 7; ++j) {
                    ab[j] = rAB[ph*7 + j];
                    cb[j] = rC [ph*7 + j];
                }
                #pragma unroll
                for (int j = 0; j < 7; ++j) {
                    const float4 A = ab[j];
                    const float2 C = cb[j];
                    float e0 = A.x - oc0, e1 = A.y - oc1, e2 = A.z - oc2;
                    float d0 = A.w - sc0, d1 = C.x - sc1, d2 = C.y - sc2;
                    if constexpr (MASKED) {
                        e0 = (A.x > 0.f) ? e0 : 0.f;
                        e1 = (A.y > 0.f) ? e1 : 0.f;
                        e2 = (A.z > 0.f) ? e2 : 0.f;
                        d0 = (A.w > 0.f) ? d0 : 0.f;
                        d1 = (C.x > 0.f) ? d1 : 0.f;
                        d2 = (C.y > 0.f) ? d2 : 0.f;
                    }
                    er_o += fabsf(e0); er_o += fabsf(e1); er_o += fabsf(e2);
                    float cd = fmaf(e2, e2, fmaf(e1, e1, e0*e0));
                    float g  = NSC * cd;                        // wr exponent
                    float u0 = fabsf(d0) + EPSV;                // |d|+eps
                    float u1 = fabsf(d1) + EPSV;
                    float u2 = fabsf(d2) + EPSV;
                    er_u += u0; er_u += u1; er_u += u2;
                    float tt = fmaf(d2, d2, fmaf(d1, d1, d0*d0));  // t^2
                    srow = fmaf(WXT[ph*7 + j], tt, srow);       // literal
                    // wr*(t+eps)^0.8 = exp2(0.8*log2(|d|+eps) + NSC*cd)
                    float q0 = fexp2(fmaf(LPW, flog2(u0), g));
                    float q1 = fexp2(fmaf(LPW, flog2(u1), g));
                    float q2 = fexp2(fmaf(LPW, flog2(u2), g));
                    ss += q0; ss += q1; ss += q2;
                }
            }
            sl = fmaf(wy, srow, sl);
        }
    };
    if (interior) scan(BoolC<false>{});
    else          scan(BoolC<true>{});

    racc0[tid]=er_o; racc1[tid]=er_u; racc2[tid]=sl; racc3[tid]=ss;
    __syncthreads();

    // ---- per-pixel combine across the 7 waves, select, reduce, atomic ----
    if (tid < 64) {
        float eo=0.f, es=0.f, l=0.f, s=0.f;
        #pragma unroll
        for (int k = 0; k < 7; ++k) {
            int idx = tid + 64 * k;
            eo += racc0[idx]; es += racc1[idx];
            l  += racc2[idx]; s  += racc3[idx];
        }
        es -= EPS_CORR;                      // undo the +eps per |d| term
        bool use_large = (eo < C1T) && ((es - eo) > C2T);
        float contrib = use_large ? (ALPHA_W * l) : s;
        #pragma unroll
        for (int off = 32; off > 0; off >>= 1)
            contrib += __shfl_down(contrib, off, 64);
        if (tid == 0)
            atomicAdd(out, contrib * SCALEF);
    }
}

extern "C" void kernel_launch(void* const* d_in, const int* in_sizes, int n_in,
                              void* d_out, int out_size, void* d_ws, size_t ws_size,
                              hipStream_t stream) {
    const float* orig = (const float*)d_in[0];   // original_images
    const float* smo  = (const float*)d_in[1];   // smooth_images
    float* out = (float*)d_out;

    hipMemsetAsync(d_out, 0, sizeof(float), stream);
    smooth_loss_fused<<<NBLK, NTHR, 0, stream>>>(orig, smo, out);
}

// Round 16
// 93.200 us; speedup vs baseline: 1.0460x; 1.0460x over previous
//
#include <hip/hip_runtime.h>

// Smoothness loss, 1x3x224x224 f32, scalar f32 out.
// 32x2 tiles (784 blocks) but 1024 threads = 16 waves/block:
// waves 0-4 own window rows {wv, wv+16}, waves 5-15 own row {wv}.
// -> critical path 42 iters (was 63) and up to 32 waves/CU residency
// (was 8.6) to hide LDS + trans latency. Rolled row loop, float4+float2
// LDS packing, interior/border variants, literal spatial weights.

#define WSR 10
#define KK  21
#define HH  224
#define WW  224
#define HWSZ (HH*WW)
#define SIG_COLOR 50.0f
#define LPW 0.8f
#define C1T 10.0f
#define C2T 5.0f
#define ALPHA_W 5.0f
#define EPSV 1e-6f
#define LOG2E 1.44269504088896f
#define NSC (-SIG_COLOR * LOG2E)     // exp(-sc*cd) = exp2(NSC*cd)
#define SSP ((1.0f/98.0f) * LOG2E)   // exp(-d^2/98) = exp2(-SSP*d^2)

#define TX 32
#define TY 2
#define HALO_W (TX + 2*WSR)      // 52
#define HALO_H (TY + 2*WSR)      // 22
#define HSZ (HALO_W * HALO_H)    // 1144
#define NBX (WW / TX)            // 7
#define NBY (HH / TY)            // 112
#define NBLK (NBX * NBY)         // 784
#define NTHR 1024
#define NWAVE 16
#define SCALEF (1.0f / ((float)HWSZ * 100.0f))
#define EPS_CORR (1323.0f * EPSV)    // 441 neighbors * 3 channels * eps

__device__ __forceinline__ float fexp2(float x) { return __builtin_amdgcn_exp2f(x); }
__device__ __forceinline__ float flog2(float x) { return __builtin_amdgcn_logf(x); }

template<bool B> struct BoolC { static constexpr bool value = B; };

// exp(-(k-10)^2/98) as compile-time literals
static constexpr float WXT[KK] = {
  0.3604486f, 0.4375650f, 0.5204496f, 0.6065307f, 0.6925675f,
  0.7748383f, 0.8493658f, 0.9122539f, 0.9600054f, 0.9898479f,
  1.0f,
  0.9898479f, 0.9600054f, 0.9122539f, 0.8493658f, 0.7748383f,
  0.6925675f, 0.6065307f, 0.5204496f, 0.4375650f, 0.3604486f };

__global__ __launch_bounds__(NTHR) void smooth_loss_fused(
    const float* __restrict__ orig, const float* __restrict__ smo,
    float* __restrict__ out)
{
    __shared__ float4 tAB[HSZ];   // (o0, o1, o2, s0)
    __shared__ float2 tC[HSZ];    // (s1, s2)
    __shared__ float racc0[NTHR], racc1[NTHR], racc2[NTHR], racc3[NTHR];

    const int tid = threadIdx.x;
    const int bid = blockIdx.x;
    const int bx  = bid % NBX;
    const int by  = bid / NBX;           // pixel-row-pair 0..111

    // ---- stage zero-padded halo tile (52 x 22) ----
    const int gx0 = bx * TX - WSR;
    const int gy0 = by * TY - WSR;
    for (int i = tid; i < HSZ; i += NTHR) {
        int r = i / HALO_W;
        int c = i - r * HALO_W;
        int gy = gy0 + r, gx = gx0 + c;
        bool v = ((unsigned)gy < (unsigned)HH) & ((unsigned)gx < (unsigned)WW);
        int gi = gy * WW + gx;
        float o0=0.f,o1=0.f,o2=0.f,s0=0.f,s1=0.f,s2=0.f;
        if (v) {
            o0 = orig[gi]; o1 = orig[gi+HWSZ]; o2 = orig[gi+2*HWSZ];
            s0 = smo[gi];  s1 = smo[gi+HWSZ]; s2 = smo[gi+2*HWSZ];
        }
        tAB[i] = make_float4(o0,o1,o2,s0);
        tC[i]  = make_float2(s1,s2);
    }
    __syncthreads();

    // ---- window scan: wave wv<5 owns rows {wv, wv+16}; wv>=5 owns {wv} ----
    const int lane = tid & 63;
    const int wv   = tid >> 6;           // 0..15
    const int pr   = lane >> 5;          // pixel row in tile (0..1)
    const int pc   = lane & 31;          // pixel col in tile

    const int cpos = (WSR + pr) * HALO_W + (WSR + pc);
    const float4 cAB = tAB[cpos]; const float2 cC = tC[cpos];
    const float oc0=cAB.x, oc1=cAB.y, oc2=cAB.z, sc0=cAB.w, sc1=cC.x, sc2=cC.y;

    float er_o=0.f, er_u=0.f, sl=0.f, ss=0.f;   // er_u = sum(|d|+eps)

    // interior tile: whole 52x22 halo inside image -> masks provably true
    const bool interior = (bx >= 1) & (bx <= 5) & (by >= 5) & (by <= 106);

    const int nrows = (wv < 5) ? 2 : 1;

    auto scan = [&](auto mc) {
        constexpr bool MASKED = decltype(mc)::value;
        #pragma unroll 1                     // rolled: body = 1 row
        for (int r = 0; r < nrows; ++r) {
            const int ky = wv + (r << 4);    // wv or wv+16 (0..20)
            const float dyf = (float)(ky - WSR);
            const float wy = fexp2(-SSP * dyf * dyf);
            const int rbase = (pr + ky) * HALO_W + pc;
            const float4* __restrict__ rAB = &tAB[rbase];
            const float2* __restrict__ rC  = &tC[rbase];
            float srow = 0.f;
            #pragma unroll
            for (int kx = 0; kx < KK; ++kx) {
                float4 A = rAB[kx];
                float2 C = rC[kx];
                float e0 = A.x - oc0, e1 = A.y - oc1, e2 = A.z - oc2;
                float d0 = A.w - sc0, d1 = C.x - sc1, d2 = C.y - sc2;
                if constexpr (MASKED) {
                    e0 = (A.x > 0.f) ? e0 : 0.f;
                    e1 = (A.y > 0.f) ? e1 : 0.f;
                    e2 = (A.z > 0.f) ? e2 : 0.f;
                    d0 = (A.w > 0.f) ? d0 : 0.f;
                    d1 = (C.x > 0.f) ? d1 : 0.f;
                    d2 = (C.y > 0.f) ? d2 : 0.f;
                }
                er_o += fabsf(e0); er_o += fabsf(e1); er_o += fabsf(e2);
                float cd = fmaf(e2, e2, fmaf(e1, e1, e0*e0));
                float g  = NSC * cd;                        // wr exponent
                float u0 = fabsf(d0) + EPSV;                // |d|+eps
                float u1 = fabsf(d1) + EPSV;
                float u2 = fabsf(d2) + EPSV;
                er_u += u0; er_u += u1; er_u += u2;
                float tt = fmaf(d2, d2, fmaf(d1, d1, d0*d0));  // t^2
                srow = fmaf(WXT[kx], tt, srow);             // literal weight
                // wr*(t+eps)^0.8 = exp2(0.8*log2(|d|+eps) + NSC*cd)
                float q0 = fexp2(fmaf(LPW, flog2(u0), g));
                float q1 = fexp2(fmaf(LPW, flog2(u1), g));
                float q2 = fexp2(fmaf(LPW, flog2(u2), g));
                ss += q0; ss += q1; ss += q2;
            }
            sl = fmaf(wy, srow, sl);
        }
    };
    if (interior) scan(BoolC<false>{});
    else          scan(BoolC<true>{});

    racc0[tid]=er_o; racc1[tid]=er_u; racc2[tid]=sl; racc3[tid]=ss;
    __syncthreads();

    // ---- per-pixel combine across the 16 waves, select, reduce, atomic ----
    if (tid < 64) {
        float eo=0.f, es=0.f, l=0.f, s=0.f;
        #pragma unroll
        for (int k = 0; k < NWAVE; ++k) {
            int idx = tid + 64 * k;
            eo += racc0[idx]; es += racc1[idx];
            l  += racc2[idx]; s  += racc3[idx];
        }
        es -= EPS_CORR;                      // undo the +eps per |d| term
        bool use_large = (eo < C1T) && ((es - eo) > C2T);
        float contrib = use_large ? (ALPHA_W * l) : s;
        #pragma unroll
        for (int off = 32; off > 0; off >>= 1)
            contrib += __shfl_down(contrib, off, 64);
        if (tid == 0)
            atomicAdd(out, contrib * SCALEF);
    }
}

extern "C" void kernel_launch(void* const* d_in, const int* in_sizes, int n_in,
                              void* d_out, int out_size, void* d_ws, size_t ws_size,
                              hipStream_t stream) {
    const float* orig = (const float*)d_in[0];   // original_images
    const float* smo  = (const float*)d_in[1];   // smooth_images
    float* out = (float*)d_out;

    hipMemsetAsync(d_out, 0, sizeof(float), stream);
    smooth_loss_fused<<<NBLK, NTHR, 0, stream>>>(orig, smo, out);
}